// Round 1
// baseline (807.891 us; speedup 1.0000x reference)
//
#include <hip/hip_runtime.h>

#define S_LEN 2048
#define DK 64
#define MT 64          // q rows per block
#define NT 64          // k cols per tile step
#define LD 72          // LDS row stride in ushort (16B-aligned, 2-way max read conflict)

typedef __attribute__((ext_vector_type(8))) short bf16x8;
typedef __attribute__((ext_vector_type(4))) float floatx4;

__device__ inline unsigned short f2bf(float f) {
    union { float f; unsigned u; } v; v.f = f;
    unsigned r = v.u + 0x7FFFu + ((v.u >> 16) & 1u);   // round-to-nearest-even
    return (unsigned short)(r >> 16);
}

__global__ __launch_bounds__(256) void sdpa_kernel(
    const float* __restrict__ Q, const float* __restrict__ K,
    const float* __restrict__ V, const int* __restrict__ mask,
    float* __restrict__ O, float* __restrict__ W)
{
    __shared__ alignas(16) unsigned short qs[MT * LD];
    __shared__ alignas(16) unsigned short ks[NT * LD];
    __shared__ alignas(16) unsigned short vs[DK * LD];   // transposed: vs[d][k]
    __shared__ alignas(16) unsigned short ps[MT * LD];
    __shared__ float addm[NT];

    const int tid  = threadIdx.x;
    const int wave = tid >> 6;
    const int lane = tid & 63;
    const int quad = lane >> 4;
    const int l16  = lane & 15;

    const int head = blockIdx.y;          // 0..31 = b*16+h
    const int bidx = head >> 4;
    const int q0   = blockIdx.x * MT;

    const float* Qh = Q + (size_t)head * S_LEN * DK;
    const float* Kh = K + (size_t)head * S_LEN * DK;
    const float* Vh = V + (size_t)head * S_LEN * DK;
    const int*   mk = mask + bidx * S_LEN;
    float* Wh = W + (size_t)head * S_LEN * S_LEN;
    float* Oh = O + (size_t)head * S_LEN * DK;

    // ---- stage Q tile (64x64 fp32 -> bf16), perfectly coalesced ----
    #pragma unroll
    for (int i = 0; i < 4; ++i) {
        const int g   = i * 256 + tid;        // 16B-chunk id
        const int row = g >> 4;
        const int col = (g & 15) * 4;
        float4 f = *(const float4*)(Qh + (size_t)(q0 + row) * DK + col);
        unsigned* d = (unsigned*)&qs[row * LD + col];
        d[0] = f2bf(f.x) | ((unsigned)f2bf(f.y) << 16);
        d[1] = f2bf(f.z) | ((unsigned)f2bf(f.w) << 16);
    }
    __syncthreads();

    // persistent A-fragments of Q (A[m=lane&15][k=quad*8+j], halves of d)
    const bf16x8 qa0 = *(const bf16x8*)&qs[(wave * 16 + l16) * LD + quad * 8];
    const bf16x8 qa1 = *(const bf16x8*)&qs[(wave * 16 + l16) * LD + 32 + quad * 8];

    float m[4], l[4];
    #pragma unroll
    for (int r = 0; r < 4; ++r) { m[r] = -1e30f; l[r] = 0.0f; }

    // ================= pass 1: online softmax stats =================
    for (int kt = 0; kt < S_LEN / NT; ++kt) {
        #pragma unroll
        for (int i = 0; i < 4; ++i) {
            const int g   = i * 256 + tid;
            const int row = g >> 4;
            const int col = (g & 15) * 4;
            float4 f = *(const float4*)(Kh + (size_t)(kt * NT + row) * DK + col);
            unsigned* d = (unsigned*)&ks[row * LD + col];
            d[0] = f2bf(f.x) | ((unsigned)f2bf(f.y) << 16);
            d[1] = f2bf(f.z) | ((unsigned)f2bf(f.w) << 16);
        }
        if (tid < NT) addm[tid] = mk[kt * NT + tid] ? 0.0f : -1e30f;
        __syncthreads();

        floatx4 acc[4];
        #pragma unroll
        for (int c = 0; c < 4; ++c) {
            bf16x8 b0 = *(const bf16x8*)&ks[(c * 16 + l16) * LD + quad * 8];
            bf16x8 b1 = *(const bf16x8*)&ks[(c * 16 + l16) * LD + 32 + quad * 8];
            floatx4 z = {0.f, 0.f, 0.f, 0.f};
            z = __builtin_amdgcn_mfma_f32_16x16x32_bf16(qa0, b0, z, 0, 0, 0);
            z = __builtin_amdgcn_mfma_f32_16x16x32_bf16(qa1, b1, z, 0, 0, 0);
            acc[c] = z;
        }

        float sv[4][4];
        #pragma unroll
        for (int c = 0; c < 4; ++c) {
            float am = addm[c * 16 + l16];
            #pragma unroll
            for (int r = 0; r < 4; ++r)
                sv[c][r] = acc[c][r] * 0.125f + am;
        }
        #pragma unroll
        for (int r = 0; r < 4; ++r) {
            float tmax = fmaxf(fmaxf(sv[0][r], sv[1][r]), fmaxf(sv[2][r], sv[3][r]));
            #pragma unroll
            for (int off = 1; off < 16; off <<= 1)
                tmax = fmaxf(tmax, __shfl_xor(tmax, off, 64));
            float mn = fmaxf(m[r], tmax);
            float ts = __expf(sv[0][r] - mn) + __expf(sv[1][r] - mn)
                     + __expf(sv[2][r] - mn) + __expf(sv[3][r] - mn);
            #pragma unroll
            for (int off = 1; off < 16; off <<= 1)
                ts += __shfl_xor(ts, off, 64);
            l[r] = l[r] * __expf(m[r] - mn) + ts;
            m[r] = mn;
        }
        __syncthreads();
    }

    float rl[4];
    #pragma unroll
    for (int r = 0; r < 4; ++r) rl[r] = 1.0f / l[r];

    // ================= pass 2: weights + O = P*V =================
    floatx4 oacc[4];
    #pragma unroll
    for (int c = 0; c < 4; ++c) oacc[c] = (floatx4){0.f, 0.f, 0.f, 0.f};

    for (int kt = 0; kt < S_LEN / NT; ++kt) {
        #pragma unroll
        for (int i = 0; i < 4; ++i) {
            const int g   = i * 256 + tid;
            const int row = g >> 4;
            const int col = (g & 15) * 4;
            float4 f = *(const float4*)(Kh + (size_t)(kt * NT + row) * DK + col);
            unsigned* d = (unsigned*)&ks[row * LD + col];
            d[0] = f2bf(f.x) | ((unsigned)f2bf(f.y) << 16);
            d[1] = f2bf(f.z) | ((unsigned)f2bf(f.w) << 16);
        }
        {   // stage V transposed: vs[d][k]
            const int row  = tid >> 2;            // local k
            const int colg = (tid & 3) << 4;      // d base
            const float4* vsrc = (const float4*)(Vh + (size_t)(kt * NT + row) * DK + colg);
            #pragma unroll
            for (int i = 0; i < 4; ++i) {
                float4 f = vsrc[i];
                const int dbase = colg + i * 4;
                vs[(dbase + 0) * LD + row] = f2bf(f.x);
                vs[(dbase + 1) * LD + row] = f2bf(f.y);
                vs[(dbase + 2) * LD + row] = f2bf(f.z);
                vs[(dbase + 3) * LD + row] = f2bf(f.w);
            }
        }
        if (tid < NT) addm[tid] = mk[kt * NT + tid] ? 0.0f : -1e30f;
        __syncthreads();

        floatx4 acc[4];
        #pragma unroll
        for (int c = 0; c < 4; ++c) {
            bf16x8 b0 = *(const bf16x8*)&ks[(c * 16 + l16) * LD + quad * 8];
            bf16x8 b1 = *(const bf16x8*)&ks[(c * 16 + l16) * LD + 32 + quad * 8];
            floatx4 z = {0.f, 0.f, 0.f, 0.f};
            z = __builtin_amdgcn_mfma_f32_16x16x32_bf16(qa0, b0, z, 0, 0, 0);
            z = __builtin_amdgcn_mfma_f32_16x16x32_bf16(qa1, b1, z, 0, 0, 0);
            acc[c] = z;
        }

        // final weights: write to global W (fp32) and to LDS ps (bf16, A-layout source)
        #pragma unroll
        for (int c = 0; c < 4; ++c) {
            float am = addm[c * 16 + l16];
            #pragma unroll
            for (int r = 0; r < 4; ++r) {
                const int lrow = wave * 16 + quad * 4 + r;
                float w = __expf(acc[c][r] * 0.125f + am - m[r]) * rl[r];
                Wh[(size_t)(q0 + lrow) * S_LEN + kt * NT + c * 16 + l16] = w;
                ps[lrow * LD + c * 16 + l16] = f2bf(w);
            }
        }
        __syncthreads();

        bf16x8 pa0 = *(const bf16x8*)&ps[(wave * 16 + l16) * LD + quad * 8];
        bf16x8 pa1 = *(const bf16x8*)&ps[(wave * 16 + l16) * LD + 32 + quad * 8];
        #pragma unroll
        for (int c = 0; c < 4; ++c) {
            bf16x8 v0 = *(const bf16x8*)&vs[(c * 16 + l16) * LD + quad * 8];
            bf16x8 v1 = *(const bf16x8*)&vs[(c * 16 + l16) * LD + 32 + quad * 8];
            oacc[c] = __builtin_amdgcn_mfma_f32_16x16x32_bf16(pa0, v0, oacc[c], 0, 0, 0);
            oacc[c] = __builtin_amdgcn_mfma_f32_16x16x32_bf16(pa1, v1, oacc[c], 0, 0, 0);
        }
        __syncthreads();
    }

    // ---- epilogue: write O ----
    #pragma unroll
    for (int c = 0; c < 4; ++c) {
        #pragma unroll
        for (int r = 0; r < 4; ++r) {
            const int lrow = wave * 16 + quad * 4 + r;
            Oh[(size_t)(q0 + lrow) * DK + c * 16 + l16] = oacc[c][r];
        }
    }
}

extern "C" void kernel_launch(void* const* d_in, const int* in_sizes, int n_in,
                              void* d_out, int out_size, void* d_ws, size_t ws_size,
                              hipStream_t stream) {
    const float* Q  = (const float*)d_in[0];
    const float* K  = (const float*)d_in[1];
    const float* V  = (const float*)d_in[2];
    const int* mask = (const int*)d_in[3];

    float* O = (float*)d_out;                                  // [2,16,2048,64]
    float* W = (float*)d_out + (size_t)2 * 16 * 2048 * 64;     // [2,16,2048,2048]

    dim3 grid(S_LEN / MT, 32);
    sdpa_kernel<<<grid, 256, 0, stream>>>(Q, K, V, mask, O, W);
}

// Round 2
// 681.601 us; speedup vs baseline: 1.1853x; 1.1853x over previous
//
#include <hip/hip_runtime.h>
#include <stdint.h>

#define S_LEN 2048
#define DK 64
#define MT 64          // q rows per block
#define NT 64          // k cols per tile step
#define LDP 72         // ps stride in ushort (144B, 16B-aligned)

typedef __attribute__((ext_vector_type(8))) short bf16x8;
typedef __attribute__((ext_vector_type(4))) float floatx4;

__device__ inline unsigned short f2bf(float f) {
    union { float f; unsigned u; } v; v.f = f;
    unsigned r = v.u + 0x7FFFu + ((v.u >> 16) & 1u);   // RNE
    return (unsigned short)(r >> 16);
}

// async global->LDS, 16B per lane. LDS dest = wave-uniform base + lane*16;
// we pass per-lane l = base + lane*16 so both semantics agree.
__device__ inline void async16(const void* g, void* l) {
    using gu32 = const __attribute__((address_space(1))) unsigned int;
    using lu32 = __attribute__((address_space(3))) unsigned int;
    gu32* gp = reinterpret_cast<gu32*>(reinterpret_cast<uintptr_t>(g));
    lu32* lp = reinterpret_cast<lu32*>(static_cast<unsigned int>(reinterpret_cast<uintptr_t>(l)));
    __builtin_amdgcn_global_load_lds(gp, lp, 16, 0, 0);
}

// ---------------- prologue: fp32 -> bf16 conversions ----------------
// Q gets the 1/sqrt(64)=0.125 scale folded in (exact in bf16: pow2).
__global__ __launch_bounds__(256) void convert_qk(
    const float* __restrict__ Q, const float* __restrict__ K,
    unsigned short* __restrict__ Qb, unsigned short* __restrict__ Kb)
{
    int i = blockIdx.x * 256 + threadIdx.x;        // 0 .. 2M-1 float4 chunks
    const int NQ = (2 * 16 * 2048 * 64) / 4;       // 1,048,576
    const float* src; unsigned short* dst; int j; float sc;
    if (i < NQ) { src = Q; dst = Qb; j = i; sc = 0.125f; }
    else        { src = K; dst = Kb; j = i - NQ; sc = 1.0f; }
    float4 f = ((const float4*)src)[j];
    ushort4 o;
    o.x = f2bf(f.x * sc); o.y = f2bf(f.y * sc);
    o.z = f2bf(f.z * sc); o.w = f2bf(f.w * sc);
    ((ushort4*)dst)[j] = o;
}

// V [head][k][d] fp32  ->  Vt [head][d][k] bf16, 64x64 tiles via LDS
__global__ __launch_bounds__(256) void transpose_v(
    const float* __restrict__ V, unsigned short* __restrict__ Vt)
{
    __shared__ unsigned short t[64][72];
    const int head = blockIdx.y, kt = blockIdx.x, tid = threadIdx.x;
    const float* src = V + ((size_t)head * S_LEN + kt * 64) * DK;
    {
        const int r = tid >> 2, c = (tid & 3) * 16;
        #pragma unroll
        for (int i = 0; i < 4; ++i) {
            float4 f = *(const float4*)(src + r * DK + c + i * 4);
            t[r][c + i * 4 + 0] = f2bf(f.x);
            t[r][c + i * 4 + 1] = f2bf(f.y);
            t[r][c + i * 4 + 2] = f2bf(f.z);
            t[r][c + i * 4 + 3] = f2bf(f.w);
        }
    }
    __syncthreads();
    {
        const int d = tid >> 2, kb = (tid & 3) * 16;
        unsigned short tmp[16];
        #pragma unroll
        for (int j = 0; j < 16; ++j) tmp[j] = t[kb + j][d];
        unsigned short* dst = Vt + (size_t)head * DK * S_LEN + (size_t)d * S_LEN + kt * 64 + kb;
        ((uint4*)dst)[0] = *(const uint4*)&tmp[0];
        ((uint4*)dst)[1] = *(const uint4*)&tmp[8];
    }
}

// ---------------- main kernel ----------------
__global__ __launch_bounds__(256) void sdpa_main(
    const unsigned short* __restrict__ Qb, const unsigned short* __restrict__ Kb,
    const unsigned short* __restrict__ Vt, const int* __restrict__ mask,
    float* __restrict__ O, float* __restrict__ W)
{
    __shared__ alignas(16) unsigned short qs[MT * DK];   // unpadded (global_load_lds)
    __shared__ alignas(16) unsigned short ks[NT * DK];
    __shared__ alignas(16) unsigned short vs[DK * NT];   // [d][k]
    __shared__ alignas(16) unsigned short ps[MT * LDP];

    const int tid  = threadIdx.x;
    const int wave = tid >> 6;
    const int lane = tid & 63;
    const int quad = lane >> 4;
    const int l16  = lane & 15;

    const int head = blockIdx.y;
    const int bidx = head >> 4;
    const int q0   = blockIdx.x * MT;

    const unsigned short* Qh = Qb + ((size_t)head * S_LEN + q0) * DK;
    const unsigned short* Kh = Kb + (size_t)head * S_LEN * DK;
    const unsigned short* Vh = Vt + (size_t)head * DK * S_LEN;
    const int*   mk = mask + bidx * S_LEN;
    float* Wh = W + (size_t)head * S_LEN * S_LEN;
    float* Oh = O + (size_t)head * S_LEN * DK;

    // stage Q tile (contiguous 8 KB)
    {
        const int o0 = wave * 2048 + lane * 16;
        async16((const char*)Qh + o0,        (char*)qs + o0);
        async16((const char*)Qh + o0 + 1024, (char*)qs + o0 + 1024);
    }
    __syncthreads();
    const bf16x8 qa0 = *(const bf16x8*)&qs[(wave * 16 + l16) * DK + quad * 8];
    const bf16x8 qa1 = *(const bf16x8*)&qs[(wave * 16 + l16) * DK + 32 + quad * 8];

    // ============ pass 1: denominators only (no max needed) ============
    float lsum[4] = {0.f, 0.f, 0.f, 0.f};
    for (int kt = 0; kt < S_LEN / NT; ++kt) {
        {
            const char* gb = (const char*)Kh + kt * 8192;
            const int o0 = wave * 2048 + lane * 16;
            async16(gb + o0,        (char*)ks + o0);
            async16(gb + o0 + 1024, (char*)ks + o0 + 1024);
        }
        float mf[4];
        #pragma unroll
        for (int c = 0; c < 4; ++c)
            mf[c] = mk[kt * NT + c * 16 + l16] ? 1.0f : 0.0f;
        __syncthreads();
        #pragma unroll
        for (int c = 0; c < 4; ++c) {
            bf16x8 b0 = *(const bf16x8*)&ks[(c * 16 + l16) * DK + quad * 8];
            bf16x8 b1 = *(const bf16x8*)&ks[(c * 16 + l16) * DK + 32 + quad * 8];
            floatx4 z = {0.f, 0.f, 0.f, 0.f};
            z = __builtin_amdgcn_mfma_f32_16x16x32_bf16(qa0, b0, z, 0, 0, 0);
            z = __builtin_amdgcn_mfma_f32_16x16x32_bf16(qa1, b1, z, 0, 0, 0);
            #pragma unroll
            for (int r = 0; r < 4; ++r)
                lsum[r] += __expf(z[r]) * mf[c];
        }
        __syncthreads();   // WAR before next staging
    }
    float rl[4];
    #pragma unroll
    for (int r = 0; r < 4; ++r) {
        float s = lsum[r];
        #pragma unroll
        for (int off = 1; off < 16; off <<= 1)
            s += __shfl_xor(s, off, 64);
        rl[r] = 1.0f / s;
    }

    // ============ pass 2: W + O ============
    floatx4 oacc[4];
    #pragma unroll
    for (int c = 0; c < 4; ++c) oacc[c] = (floatx4){0.f, 0.f, 0.f, 0.f};

    for (int kt = 0; kt < S_LEN / NT; ++kt) {
        {
            const char* gb = (const char*)Kh + kt * 8192;
            const int o0 = wave * 2048 + lane * 16;
            async16(gb + o0,        (char*)ks + o0);
            async16(gb + o0 + 1024, (char*)ks + o0 + 1024);
        }
        {   // Vt tile: LDS [d][k] rows; global gathered per lane
            const int o0 = wave * 2048 + lane * 16;
            #pragma unroll
            for (int j = 0; j < 2; ++j) {
                const int o = o0 + j * 1024;
                const int d = o >> 7;       // LDS byte/128 -> d row
                const int kb = o & 127;     // byte within row
                async16((const char*)Vh + (size_t)d * 4096 + kt * 128 + kb, (char*)vs + o);
            }
        }
        float mf[4];
        #pragma unroll
        for (int c = 0; c < 4; ++c)
            mf[c] = mk[kt * NT + c * 16 + l16] ? 1.0f : 0.0f;
        __syncthreads();

        floatx4 acc[4];
        #pragma unroll
        for (int c = 0; c < 4; ++c) {
            bf16x8 b0 = *(const bf16x8*)&ks[(c * 16 + l16) * DK + quad * 8];
            bf16x8 b1 = *(const bf16x8*)&ks[(c * 16 + l16) * DK + 32 + quad * 8];
            floatx4 z = {0.f, 0.f, 0.f, 0.f};
            z = __builtin_amdgcn_mfma_f32_16x16x32_bf16(qa0, b0, z, 0, 0, 0);
            z = __builtin_amdgcn_mfma_f32_16x16x32_bf16(qa1, b1, z, 0, 0, 0);
            acc[c] = z;
        }

        #pragma unroll
        for (int c = 0; c < 4; ++c) {
            #pragma unroll
            for (int r = 0; r < 4; ++r) {
                const int lrow = wave * 16 + quad * 4 + r;
                float w = __expf(acc[c][r]) * rl[r] * mf[c];
                Wh[(size_t)(q0 + lrow) * S_LEN + kt * NT + c * 16 + l16] = w;
                ps[lrow * LDP + c * 16 + l16] = f2bf(w);
            }
        }
        // same-wave LDS RAW (rows wave*16..+15): in-order LDS + compiler waitcnt
        bf16x8 pa0 = *(const bf16x8*)&ps[(wave * 16 + l16) * LDP + quad * 8];
        bf16x8 pa1 = *(const bf16x8*)&ps[(wave * 16 + l16) * LDP + 32 + quad * 8];
        #pragma unroll
        for (int c = 0; c < 4; ++c) {
            bf16x8 v0 = *(const bf16x8*)&vs[(c * 16 + l16) * DK + quad * 8];
            bf16x8 v1 = *(const bf16x8*)&vs[(c * 16 + l16) * DK + 32 + quad * 8];
            oacc[c] = __builtin_amdgcn_mfma_f32_16x16x32_bf16(pa0, v0, oacc[c], 0, 0, 0);
            oacc[c] = __builtin_amdgcn_mfma_f32_16x16x32_bf16(pa1, v1, oacc[c], 0, 0, 0);
        }
        __syncthreads();   // WAR: ks/vs re-staged, ps rewritten next iter
    }

    #pragma unroll
    for (int c = 0; c < 4; ++c) {
        #pragma unroll
        for (int r = 0; r < 4; ++r) {
            const int lrow = wave * 16 + quad * 4 + r;
            Oh[(size_t)(q0 + lrow) * DK + c * 16 + l16] = oacc[c][r];
        }
    }
}

// ---------------- fallback (R1 kernel, used only if ws too small) ----------------
#define LD 72
__global__ __launch_bounds__(256) void sdpa_fb(
    const float* __restrict__ Q, const float* __restrict__ K,
    const float* __restrict__ V, const int* __restrict__ mask,
    float* __restrict__ O, float* __restrict__ W)
{
    __shared__ alignas(16) unsigned short qs[MT * LD];
    __shared__ alignas(16) unsigned short ks[NT * LD];
    __shared__ alignas(16) unsigned short vs[DK * LD];
    __shared__ alignas(16) unsigned short ps[MT * LD];
    __shared__ float addm[NT];

    const int tid = threadIdx.x, wave = tid >> 6, lane = tid & 63;
    const int quad = lane >> 4, l16 = lane & 15;
    const int head = blockIdx.y, bidx = head >> 4, q0 = blockIdx.x * MT;

    const float* Qh = Q + (size_t)head * S_LEN * DK;
    const float* Kh = K + (size_t)head * S_LEN * DK;
    const float* Vh = V + (size_t)head * S_LEN * DK;
    const int* mk = mask + bidx * S_LEN;
    float* Wh = W + (size_t)head * S_LEN * S_LEN;
    float* Oh = O + (size_t)head * S_LEN * DK;

    #pragma unroll
    for (int i = 0; i < 4; ++i) {
        const int g = i * 256 + tid, row = g >> 4, col = (g & 15) * 4;
        float4 f = *(const float4*)(Qh + (size_t)(q0 + row) * DK + col);
        unsigned* d = (unsigned*)&qs[row * LD + col];
        d[0] = f2bf(f.x) | ((unsigned)f2bf(f.y) << 16);
        d[1] = f2bf(f.z) | ((unsigned)f2bf(f.w) << 16);
    }
    __syncthreads();
    const bf16x8 qa0 = *(const bf16x8*)&qs[(wave * 16 + l16) * LD + quad * 8];
    const bf16x8 qa1 = *(const bf16x8*)&qs[(wave * 16 + l16) * LD + 32 + quad * 8];

    float m[4], l[4];
    #pragma unroll
    for (int r = 0; r < 4; ++r) { m[r] = -1e30f; l[r] = 0.0f; }

    for (int kt = 0; kt < S_LEN / NT; ++kt) {
        #pragma unroll
        for (int i = 0; i < 4; ++i) {
            const int g = i * 256 + tid, row = g >> 4, col = (g & 15) * 4;
            float4 f = *(const float4*)(Kh + (size_t)(kt * NT + row) * DK + col);
            unsigned* d = (unsigned*)&ks[row * LD + col];
            d[0] = f2bf(f.x) | ((unsigned)f2bf(f.y) << 16);
            d[1] = f2bf(f.z) | ((unsigned)f2bf(f.w) << 16);
        }
        if (tid < NT) addm[tid] = mk[kt * NT + tid] ? 0.0f : -1e30f;
        __syncthreads();
        floatx4 acc[4];
        #pragma unroll
        for (int c = 0; c < 4; ++c) {
            bf16x8 b0 = *(const bf16x8*)&ks[(c * 16 + l16) * LD + quad * 8];
            bf16x8 b1 = *(const bf16x8*)&ks[(c * 16 + l16) * LD + 32 + quad * 8];
            floatx4 z = {0.f, 0.f, 0.f, 0.f};
            z = __builtin_amdgcn_mfma_f32_16x16x32_bf16(qa0, b0, z, 0, 0, 0);
            z = __builtin_amdgcn_mfma_f32_16x16x32_bf16(qa1, b1, z, 0, 0, 0);
            acc[c] = z;
        }
        float sv[4][4];
        #pragma unroll
        for (int c = 0; c < 4; ++c) {
            float am = addm[c * 16 + l16];
            #pragma unroll
            for (int r = 0; r < 4; ++r) sv[c][r] = acc[c][r] * 0.125f + am;
        }
        #pragma unroll
        for (int r = 0; r < 4; ++r) {
            float tmax = fmaxf(fmaxf(sv[0][r], sv[1][r]), fmaxf(sv[2][r], sv[3][r]));
            #pragma unroll
            for (int off = 1; off < 16; off <<= 1) tmax = fmaxf(tmax, __shfl_xor(tmax, off, 64));
            float mn = fmaxf(m[r], tmax);
            float ts = __expf(sv[0][r] - mn) + __expf(sv[1][r] - mn)
                     + __expf(sv[2][r] - mn) + __expf(sv[3][r] - mn);
            #pragma unroll
            for (int off = 1; off < 16; off <<= 1) ts += __shfl_xor(ts, off, 64);
            l[r] = l[r] * __expf(m[r] - mn) + ts;
            m[r] = mn;
        }
        __syncthreads();
    }
    float rl[4];
    #pragma unroll
    for (int r = 0; r < 4; ++r) rl[r] = 1.0f / l[r];

    floatx4 oacc[4];
    #pragma unroll
    for (int c = 0; c < 4; ++c) oacc[c] = (floatx4){0.f, 0.f, 0.f, 0.f};

    for (int kt = 0; kt < S_LEN / NT; ++kt) {
        #pragma unroll
        for (int i = 0; i < 4; ++i) {
            const int g = i * 256 + tid, row = g >> 4, col = (g & 15) * 4;
            float4 f = *(const float4*)(Kh + (size_t)(kt * NT + row) * DK + col);
            unsigned* d = (unsigned*)&ks[row * LD + col];
            d[0] = f2bf(f.x) | ((unsigned)f2bf(f.y) << 16);
            d[1] = f2bf(f.z) | ((unsigned)f2bf(f.w) << 16);
        }
        {
            const int row = tid >> 2, colg = (tid & 3) << 4;
            const float4* vsrc = (const float4*)(Vh + (size_t)(kt * NT + row) * DK + colg);
            #pragma unroll
            for (int i = 0; i < 4; ++i) {
                float4 f = vsrc[i];
                const int dbase = colg + i * 4;
                vs[(dbase + 0) * LD + row] = f2bf(f.x);
                vs[(dbase + 1) * LD + row] = f2bf(f.y);
                vs[(dbase + 2) * LD + row] = f2bf(f.z);
                vs[(dbase + 3) * LD + row] = f2bf(f.w);
            }
        }
        if (tid < NT) addm[tid] = mk[kt * NT + tid] ? 0.0f : -1e30f;
        __syncthreads();
        floatx4 acc[4];
        #pragma unroll
        for (int c = 0; c < 4; ++c) {
            bf16x8 b0 = *(const bf16x8*)&ks[(c * 16 + l16) * LD + quad * 8];
            bf16x8 b1 = *(const bf16x8*)&ks[(c * 16 + l16) * LD + 32 + quad * 8];
            floatx4 z = {0.f, 0.f, 0.f, 0.f};
            z = __builtin_amdgcn_mfma_f32_16x16x32_bf16(qa0, b0, z, 0, 0, 0);
            z = __builtin_amdgcn_mfma_f32_16x16x32_bf16(qa1, b1, z, 0, 0, 0);
            acc[c] = z;
        }
        #pragma unroll
        for (int c = 0; c < 4; ++c) {
            float am = addm[c * 16 + l16];
            #pragma unroll
            for (int r = 0; r < 4; ++r) {
                const int lrow = wave * 16 + quad * 4 + r;
                float w = __expf(acc[c][r] * 0.125f + am - m[r]) * rl[r];
                Wh[(size_t)(q0 + lrow) * S_LEN + kt * NT + c * 16 + l16] = w;
                ps[lrow * LD + c * 16 + l16] = f2bf(w);
            }
        }
        __syncthreads();
        bf16x8 pa0 = *(const bf16x8*)&ps[(wave * 16 + l16) * LD + quad * 8];
        bf16x8 pa1 = *(const bf16x8*)&ps[(wave * 16 + l16) * LD + 32 + quad * 8];
        #pragma unroll
        for (int c = 0; c < 4; ++c) {
            bf16x8 v0 = *(const bf16x8*)&vs[(c * 16 + l16) * LD + quad * 8];
            bf16x8 v1 = *(const bf16x8*)&vs[(c * 16 + l16) * LD + 32 + quad * 8];
            oacc[c] = __builtin_amdgcn_mfma_f32_16x16x32_bf16(pa0, v0, oacc[c], 0, 0, 0);
            oacc[c] = __builtin_amdgcn_mfma_f32_16x16x32_bf16(pa1, v1, oacc[c], 0, 0, 0);
        }
        __syncthreads();
    }
    #pragma unroll
    for (int c = 0; c < 4; ++c) {
        #pragma unroll
        for (int r = 0; r < 4; ++r) {
            const int lrow = wave * 16 + quad * 4 + r;
            Oh[(size_t)(q0 + lrow) * DK + c * 16 + l16] = oacc[c][r];
        }
    }
}

extern "C" void kernel_launch(void* const* d_in, const int* in_sizes, int n_in,
                              void* d_out, int out_size, void* d_ws, size_t ws_size,
                              hipStream_t stream) {
    const float* Q  = (const float*)d_in[0];
    const float* K  = (const float*)d_in[1];
    const float* V  = (const float*)d_in[2];
    const int* mask = (const int*)d_in[3];

    float* O = (float*)d_out;                                  // [2,16,2048,64]
    float* W = (float*)d_out + (size_t)2 * 16 * 2048 * 64;     // [2,16,2048,2048]

    const size_t elems = (size_t)2 * 16 * 2048 * 64;           // 4,194,304
    const size_t need  = 3 * elems * sizeof(unsigned short);   // 24 MiB

    if (ws_size >= need) {
        unsigned short* Qb = (unsigned short*)d_ws;
        unsigned short* Kb = Qb + elems;
        unsigned short* Vt = Kb + elems;
        convert_qk<<<dim3((2 * elems / 4) / 256), 256, 0, stream>>>(Q, K, Qb, Kb);
        transpose_v<<<dim3(32, 32), 256, 0, stream>>>(V, Vt);
        sdpa_main<<<dim3(S_LEN / MT, 32), 256, 0, stream>>>(Qb, Kb, Vt, mask, O, W);
    } else {
        sdpa_fb<<<dim3(S_LEN / MT, 32), 256, 0, stream>>>(Q, K, V, mask, O, W);
    }
}